// Round 8
// baseline (64.128 us; speedup 1.0000x reference)
//
#include <hip/hip_runtime.h>

#define P 7
#define NCH 256
#define NPP (P * P)          // 49 bins per (box, channel)
#define PER_BOX (NCH * NPP)  // 12544

__global__ __launch_bounds__(256) void pooler_kernel(
    const float* __restrict__ boxes,
    const int* __restrict__ batch_ids,
    const float* __restrict__ f0,
    const float* __restrict__ f1,
    const float* __restrict__ f2,
    const float* __restrict__ f3,
    float* __restrict__ out,
    int total)
{
    const int tid = blockIdx.x * 256 + threadIdx.x;
    if (tid >= total) return;            // grid tiles total exactly; never taken

    // tid -> (n, c, bin); bin -> (py, px)
    const int n   = tid / PER_BOX;
    const int rem = tid - n * PER_BOX;
    const int c   = rem / NPP;
    const int bin = rem - c * NPP;
    const int py  = bin / P;
    const int px  = bin - py * P;

    // ---- box + level ----
    const float x1i = boxes[n * 4 + 0];
    const float y1i = boxes[n * 4 + 1];
    const float x2i = boxes[n * 4 + 2];
    const float y2i = boxes[n * 4 + 3];

    const float area = (x2i - x1i) * (y2i - y1i);
    const float s = sqrtf(area);
    float lvlf = floorf(4.0f + log2f(s / 224.0f + 1e-6f));
    lvlf = fminf(fmaxf(lvlf, 2.0f), 5.0f);
    const int lvl = (int)lvlf - 2;       // 0..3

    // branchless-ish level select (all levels are square: L x L)
    const float* feat = (lvl == 0) ? f0 : (lvl == 1) ? f1 : (lvl == 2) ? f2 : f3;
    const int   L     = (lvl == 0) ? 200 : (lvl == 1) ? 100 : (lvl == 2) ? 50 : 25;
    const float scale = (lvl == 0) ? 0.25f : (lvl == 1) ? 0.125f
                      : (lvl == 2) ? 0.0625f : 0.03125f;

    const int b = batch_ids[n];

    const float x1 = x1i * scale;
    const float y1 = y1i * scale;
    const float bw = fmaxf(x2i * scale - x1, 1.0f) * (1.0f / P);
    const float bh = fmaxf(y2i * scale - y1, 1.0f) * (1.0f / P);

    const float Lf   = (float)L;
    const float Lm1  = Lf - 1.0f;
    const int   Lm2  = L - 2;

    const float* base = feat + ((size_t)b * NCH + c) * (size_t)(L * L);

    float acc = 0.0f;
#pragma unroll
    for (int sy = 0; sy < 2; ++sy) {
        const float gy = (float)py + ((float)sy + 0.5f) * 0.5f;
        const float yc = y1 + gy * bh;
        const float vy = (yc > -1.0f && yc < Lf) ? 1.0f : 0.0f;
        const float ycc = fminf(fmaxf(yc, 0.0f), Lm1);
        const int   y0  = min((int)ycc, Lm2);
        const float fy  = ycc - (float)y0;
        const float hy  = 1.0f - fy;
#pragma unroll
        for (int sx = 0; sx < 2; ++sx) {
            const float gx = (float)px + ((float)sx + 0.5f) * 0.5f;
            const float xc = x1 + gx * bw;
            const float vx = (xc > -1.0f && xc < Lf) ? 1.0f : 0.0f;
            const float xcc = fminf(fmaxf(xc, 0.0f), Lm1);
            const int   x0  = min((int)xcc, Lm2);
            const float fx  = xcc - (float)x0;
            const float hx  = 1.0f - fx;

            // always in-bounds after clamping — load unconditionally
            const float* p = base + (size_t)(y0 * L + x0);
            const float v00 = p[0];
            const float v01 = p[1];
            const float v10 = p[L];
            const float v11 = p[L + 1];

            const float w = vy * vx;     // invalid subsample contributes 0
            acc += w * (hy * (hx * v00 + fx * v01) + fy * (hx * v10 + fx * v11));
        }
    }

    out[tid] = acc * 0.25f;
}

extern "C" void kernel_launch(void* const* d_in, const int* in_sizes, int n_in,
                              void* d_out, int out_size, void* d_ws, size_t ws_size,
                              hipStream_t stream) {
    const float* boxes     = (const float*)d_in[0];
    const int*   batch_ids = (const int*)d_in[1];
    const float* f0        = (const float*)d_in[2];
    const float* f1        = (const float*)d_in[3];
    const float* f2        = (const float*)d_in[4];
    const float* f3        = (const float*)d_in[5];
    float* out = (float*)d_out;

    const int total = out_size;                    // 512*256*49 = 6,422,528
    const int blocks = (total + 255) / 256;        // 25088 exactly
    pooler_kernel<<<blocks, 256, 0, stream>>>(boxes, batch_ids, f0, f1, f2, f3,
                                              out, total);
}